// Round 17
// baseline (11951.472 us; speedup 1.0000x reference)
//
#include <hip/hip_runtime.h>

// LSTMAutoEncoder: B=64, T=512, H=512, F=32.
// Dead-code: only encoder L0 (final h,c) and decoder L0 feed the output:
//   out[:, t, :] = h_dec0_before_step(511-t) @ W_out^T + b_out
// -> 1024 sequential cell steps; batch in 8 pods of 8 rows x 32 blocks.
//
// Round 17 = round 16 with the WAITCH macro compile fix (DST parameter).
// r13's in-wave butterfly reduce (no Gr, no reduce phase, no OP3; publish
// register-direct from the GEMM waves) + r14's proven sync skeleton (ONE
// hardware barrier, mantissa-tag u32 exchange, parity-2 planes).
// Step: BAR -> GEMM(reads U[s&1]) -> butterfly -> publish(tag s+1) ->
// issue next gather -> out-proj (hides RT) -> x-stage -> WAITCH/stage into
// U[(s+1)&1] -> loop. r13's failure was intra-block flag spins (replaced by
// the barrier); r9/r13 lessons: no cross-wave flags, conflicts don't bind.

#define TT   512
#define HH   512
#define FF   32
#define PODS 8
#define BT   8
#define NTHR 256
#define NBLK 256
#define URS  580              // U row stride: 16 slices x 36 + 4 (skewed)
#define UPF  (BT * URS)       // 4640 floats per parity plane
#define UXS  34               // UX row stride
#define PUB_U32 (2 * PODS * BT * HH)   // 65536 u32 (256 KB in d_ws)

typedef float f4v __attribute__((ext_vector_type(4)));
typedef float f2v __attribute__((ext_vector_type(2)));
typedef unsigned long long u64;
typedef unsigned int u32;

__device__ __forceinline__ float sigmf(float x)    { return 1.f / (1.f + __expf(-x)); }
__device__ __forceinline__ float tanhfast(float x) { return 1.f - 2.f / (__expf(2.f * x) + 1.f); }

__global__ void init_ws_kernel(u32* pub) {
  const int i = blockIdx.x * blockDim.x + threadIdx.x;
  if (i < PUB_U32) pub[i] = 0u;   // h = 0.0f, tag byte = 0 (both parities)
}

#define LDU64(P) __hip_atomic_load((P), __ATOMIC_RELAXED, __HIP_MEMORY_SCOPE_AGENT)

// Issue chunk Q (cols 16Q+2sub,+1 of this wave's 128-col region) from base GP.
#define ISSUE(Q, GP) v[Q] = LDU64((const u64*)((GP) + 16 * (Q)))

// Wait chunk Q fresh (both mantissa-tag bytes == TG), fast retry (sleep after
// 2 rounds), strip tags, one 8B write into the skewed U plane (base DST).
#define WAITCH(Q, GP, TG, DST) do {                                            \
    unsigned lo_ = (unsigned)v[Q], hi_ = (unsigned)(v[Q] >> 32);               \
    int tries = 0;                                                             \
    while ((lo_ & 255u) != (TG) || (hi_ & 255u) != (TG)) {                     \
      if (++tries > 2) __builtin_amdgcn_s_sleep(1);                            \
      v[Q] = LDU64((const u64*)((GP) + 16 * (Q)));                             \
      lo_ = (unsigned)v[Q]; hi_ = (unsigned)(v[Q] >> 32);                      \
    }                                                                          \
    float2 st_;                                                                \
    st_.x = __uint_as_float(lo_ & ~255u);                                      \
    st_.y = __uint_as_float(hi_ & ~255u);                                      \
    *(float2*)&(DST)[36 * ((Q) >> 1) + ((Q) & 1) * 16] = st_;                  \
  } while (0)

// GEMM sub-round R: lane's cols [32ks+4R, +4) x 8 rows x 4 gates, packed f2v.
#define SUBR(R) do {                                                           \
    _Pragma("unroll")                                                          \
    for (int b = 0; b < 8; ++b) {                                              \
      const f4v u = *(const f4v*)(Ub + b * URS + 4 * (R));                     \
      f2v u01; u01[0] = u[0]; u01[1] = u[1];                                   \
      f2v u23; u23[0] = u[2]; u23[1] = u[3];                                   \
      _Pragma("unroll")                                                        \
      for (int m = 0; m < 4; ++m)                                              \
        acc2[m][b] += u01 * w01[m][R] + u23 * w23[m][R];                       \
    }                                                                          \
  } while (0)

// Lane (ks, jl) owns hidden jglob = j0+4w+jl, all 4 gates, K-cols [32ks,+32)
// of Whh + x-cols {2ks,+1} of Wih.
__device__ __forceinline__ void load_w(
    const float* __restrict__ Wih, const float* __restrict__ Whh,
    const float* __restrict__ bih, const float* __restrict__ bhh,
    int jglob, int ks, f2v w01[4][8], f2v w23[4][8], f2v wxv[4], float bias[4])
{
  #pragma unroll
  for (int m = 0; m < 4; ++m) {
    const int g = m * HH + jglob;
    #pragma unroll
    for (int q = 0; q < 8; ++q) {
      const f4v tw = *(const f4v*)&Whh[g * HH + 32 * ks + 4 * q];
      f2v a; a[0] = tw[0]; a[1] = tw[1]; w01[m][q] = a;
      f2v b; b[0] = tw[2]; b[1] = tw[3]; w23[m][q] = b;
    }
    wxv[m]  = *(const f2v*)&Wih[g * FF + 2 * ks];
    bias[m] = bih[g] + bhh[g];
  }
}

__global__ void __launch_bounds__(NTHR, 1)
lstm_ae_kernel(const float* __restrict__ x,
               const float* __restrict__ eWih, const float* __restrict__ eWhh,
               const float* __restrict__ ebih, const float* __restrict__ ebhh,
               const float* __restrict__ dWih, const float* __restrict__ dWhh,
               const float* __restrict__ dbih, const float* __restrict__ dbhh,
               const float* __restrict__ Wo,  const float* __restrict__ bo,
               float* __restrict__ out, u32* __restrict__ pub)
{
  __shared__ float U[2 * UPF];         // [2][8][URS] skewed h staging (37 KB)
  __shared__ float UX[4 * BT * UXS];   // [4][8][34]  per-wave x copy

  const int tid = threadIdx.x;
  const int blk = blockIdx.x;
  const int pod = blk & (PODS - 1);
  const int gb  = blk >> 3;            // 0..31: hidden slice j0 = gb*16
  const int b0  = pod * BT;
  const int j0  = gb * 16;

  const int w    = tid >> 6;           // wave: stages cols [128w,+128),
  const int lane = tid & 63;           //       computes hidden j0+4w..+4
  const int row  = lane >> 3;          // staging: batch row 0..7
  const int sub  = lane & 7;           // staging: col-pair offset
  const int ks   = lane >> 2;          // gemm: K-slice 0..15
  const int jl   = lane & 3;
  const int jglob = j0 + 4 * w + jl;

  f2v   w01[4][8], w23[4][8], wxv[4];
  float bias[4];
  load_w(eWih, eWhh, ebih, ebhh, jglob, ks, w01, w23, wxv, bias);

  float c_reg = 0.f;                   // lanes ks<8 own c[b=ks][jglob]
  float* UXw = UX + w * (BT * UXS);
  u64 v[8];

  // ---- prologue: stage step 0 (tags 0 from init) into plane 0 ----
  {
    const u32* gp = pub + (size_t)pod * (BT * HH) + row * HH + 128 * w + 2 * sub;
    float*     Uw = U + row * URS + 144 * w + 2 * sub;
    ISSUE(0, gp); ISSUE(1, gp); ISSUE(2, gp); ISSUE(3, gp);
    ISSUE(4, gp); ISSUE(5, gp); ISSUE(6, gp); ISSUE(7, gp);
    if (lane < 32) {   // x(t=0): full 8x32 via 2 f4v per lane
      const int xr = lane >> 2, xs = (lane & 3) << 3;
      *(f4v*)&UXw[xr * UXS + xs]     = *(const f4v*)&x[((size_t)(b0 + xr) * TT + 0) * FF + xs];
      *(f4v*)&UXw[xr * UXS + xs + 4] = *(const f4v*)&x[((size_t)(b0 + xr) * TT + 0) * FF + xs + 4];
    }
    WAITCH(0, gp, 0u, Uw); WAITCH(1, gp, 0u, Uw); WAITCH(2, gp, 0u, Uw); WAITCH(3, gp, 0u, Uw);
    WAITCH(4, gp, 0u, Uw); WAITCH(5, gp, 0u, Uw); WAITCH(6, gp, 0u, Uw); WAITCH(7, gp, 0u, Uw);
  }

  #pragma unroll 1
  for (int s = 0; s < 2 * TT; ++s) {
    const int phase = s >> 9;
    const int step  = s & 511;
    const int t     = phase ? (511 - step) : step;
    float* Ucur = U + (s & 1) * UPF;
    u32*   pwr  = pub + (size_t)(((s + 1) & 1) * PODS + pod) * (BT * HH);

    __syncthreads();   // staging(s) complete (written in step s-1 tail)

    // ---- GEMM: 8 sub-rounds over this lane's 32 K-cols ----
    f2v acc2[4][8];
    #pragma unroll
    for (int m = 0; m < 4; ++m)
      #pragma unroll
      for (int b = 0; b < 8; ++b) {
        f2v z; z[0] = (ks == 0) ? bias[m] : 0.f; z[1] = 0.f;
        acc2[m][b] = z;
      }
    const float* Ub = Ucur + 36 * ks;
    SUBR(0); SUBR(1); SUBR(2); SUBR(3);
    SUBR(4); SUBR(5); SUBR(6); SUBR(7);
    #pragma unroll
    for (int b = 0; b < 8; ++b) {      // x part
      const f2v ux = *(const f2v*)&UXw[b * UXS + 2 * ks];
      #pragma unroll
      for (int m = 0; m < 4; ++m)
        acc2[m][b] += ux * wxv[m];
    }

    // ---- in-wave K reduction: pack-sum then butterfly over ks bits ----
    float acc[4][8];
    #pragma unroll
    for (int m = 0; m < 4; ++m)
      #pragma unroll
      for (int b = 0; b < 8; ++b) {
        float a = acc2[m][b][0] + acc2[m][b][1];
        a += __shfl_xor(a, 4);
        a += __shfl_xor(a, 8);
        a += __shfl_xor(a, 16);
        a += __shfl_xor(a, 32);
        acc[m][b] = a;
      }

    // ---- lanes ks<8: batch row b=ks -> activate, update c, publish ----
    if (ks < 8) {
      float gi = acc[0][0], gf = acc[1][0], gg = acc[2][0], go = acc[3][0];
      #pragma unroll
      for (int b = 1; b < 8; ++b)
        if (ks == b) { gi = acc[0][b]; gf = acc[1][b]; gg = acc[2][b]; go = acc[3][b]; }
      const float c2 = sigmf(gf) * c_reg + sigmf(gi) * tanhfast(gg);
      const float h2 = sigmf(go) * tanhfast(c2);
      c_reg = c2;
      const unsigned pk = (__float_as_uint(h2) & ~255u)
                        | ((unsigned)(s + 1) & 255u);
      __hip_atomic_store(&pwr[ks * HH + jglob], pk,
                         __ATOMIC_RELAXED, __HIP_MEMORY_SCOPE_AGENT);
    }

    // ---- tail: issue next gather early, hide its RT under out-proj ----
    const int sn = s + 1;
    const u32* gp = (const u32*)pwr + row * HH + 128 * w + 2 * sub;
    if (sn < 2 * TT) {
      ISSUE(0, gp); ISSUE(1, gp); ISSUE(2, gp); ISSUE(3, gp);
      ISSUE(4, gp); ISSUE(5, gp); ISSUE(6, gp); ISSUE(7, gp);
    }

    // ---- decoder out-projection (reads Ucur = pre-update h(t); protected
    // by BAR(s+1): every wave arrives there only after finishing this) ----
    if (phase) {
      const int orow = 2 * w + (lane >> 5);
      const int c16  = lane & 31;
      const float* Ur = Ucur + orow * URS + 36 * (c16 >> 1) + (c16 & 1) * 16;
      const float* Wr = Wo + gb * HH + c16 * 16;
      float pj = 0.f;
      #pragma unroll
      for (int k = 0; k < 16; k += 4) {
        const f4v u  = *(const f4v*)(Ur + k);
        const f4v wo = *(const f4v*)(Wr + k);
        pj += u[0]*wo[0] + u[1]*wo[1] + u[2]*wo[2] + u[3]*wo[3];
      }
      pj += __shfl_xor(pj, 1);
      pj += __shfl_xor(pj, 2);
      pj += __shfl_xor(pj, 4);
      pj += __shfl_xor(pj, 8);
      pj += __shfl_xor(pj, 16);
      if ((lane & 31) == 0)
        out[((size_t)(b0 + orow) * TT + t) * FF + gb] = pj + bo[gb];
    }

    // ---- stage step s+1 into plane (s+1)&1 ----
    if (sn < 2 * TT) {
      const int phn = sn >> 9, stn = sn & 511;
      const int tn  = phn ? (511 - stn) : stn;
      const unsigned tgn = (unsigned)(sn & 255);
      if (lane < 32) {
        const int xr = lane >> 2, xs = (lane & 3) << 3;
        *(f4v*)&UXw[xr * UXS + xs]     = *(const f4v*)&x[((size_t)(b0 + xr) * TT + tn) * FF + xs];
        *(f4v*)&UXw[xr * UXS + xs + 4] = *(const f4v*)&x[((size_t)(b0 + xr) * TT + tn) * FF + xs + 4];
      }
      float* Uw = U + (sn & 1) * UPF + row * URS + 144 * w + 2 * sub;
      WAITCH(0, gp, tgn, Uw); WAITCH(1, gp, tgn, Uw); WAITCH(2, gp, tgn, Uw); WAITCH(3, gp, tgn, Uw);
      WAITCH(4, gp, tgn, Uw); WAITCH(5, gp, tgn, Uw); WAITCH(6, gp, tgn, Uw); WAITCH(7, gp, tgn, Uw);
      if (sn == TT)   // encoder done -> decoder weights
        load_w(dWih, dWhh, dbih, dbhh, jglob, ks, w01, w23, wxv, bias);
    }
  }
}

extern "C" void kernel_launch(void* const* d_in, const int* in_sizes, int n_in,
                              void* d_out, int out_size, void* d_ws, size_t ws_size,
                              hipStream_t stream) {
  const float* x    = (const float*)d_in[0];
  const float* eWih = (const float*)d_in[1];   // enc_Wih0 [2048,32]
  const float* eWhh = (const float*)d_in[2];   // enc_Whh0 [2048,512]
  const float* ebih = (const float*)d_in[3];
  const float* ebhh = (const float*)d_in[4];
  // d_in[5..8] enc layer 1: dead (only feeds dead decoder layer 1)
  const float* dWih = (const float*)d_in[9];   // dec_Wih0
  const float* dWhh = (const float*)d_in[10];  // dec_Whh0
  const float* dbih = (const float*)d_in[11];
  const float* dbhh = (const float*)d_in[12];
  // d_in[13..16] dec layer 1: dead (hB/cB never reach outs)
  const float* Wo   = (const float*)d_in[17];  // [32,512]
  const float* bo   = (const float*)d_in[18];  // [32]
  float* out = (float*)d_out;

  u32* pubbuf = (u32*)d_ws;                    // [2][8][8][512] tagged h (u32)

  init_ws_kernel<<<dim3((PUB_U32 + NTHR - 1) / NTHR), dim3(NTHR), 0, stream>>>(pubbuf);
  lstm_ae_kernel<<<dim3(NBLK), dim3(NTHR), 0, stream>>>(
      x, eWih, eWhh, ebih, ebhh, dWih, dWhh, dbih, dbhh, Wo, bo,
      out, pubbuf);
}

// Round 18
// 6583.233 us; speedup vs baseline: 1.8154x; 1.8154x over previous
//
#include <hip/hip_runtime.h>

// LSTMAutoEncoder: B=64, T=512, H=512, F=32.
// Dead-code: only encoder L0 (final h,c) and decoder L0 feed the output:
//   out[:, t, :] = h_dec0_before_step(511-t) @ W_out^T + b_out
// -> 1024 sequential cell steps; batch in 8 pods of 8 rows x 32 blocks.
//
// Round 18 = round 14 (best, 5.69ms: wave-private 8-chunk gather->FMA
// pipeline, ONE barrier, Gr reduce, mantissa-tag u32 exchange, deferred
// out-proj) + three surgical fixes:
//  1) ALL-8 early issue moved to right after publish (was: 4 at step tail,
//     4 mid-pipeline) -> issue-to-check distance > MALL RT, retries drop.
//  2) Vectorized Gr: 4 gates of (b,hidden) stored as one aligned f4v
//     (GRS=68, GPL=552) -> reduce reads 16x ds_read_b128 (was 64 scalar).
//  3) x-part FMA before the chunk pipeline (extra cover for WAITCH(0)).
// Lessons held: tag-waits MUST interleave with FMA (r9/r13/r17 all lost
// without it); no cross-wave flags; conflicts don't bind.

#define TT   512
#define HH   512
#define FF   32
#define KP   548              // U row stride (floats): 512 h + 32 x + pad
#define PODS 8
#define BT   8                // batch rows per pod
#define GBLK 32               // blocks per pod
#define JT   16               // hidden indices per block
#define NTHR 256
#define NBLK (PODS * GBLK)
#define GRS  68               // Gr batch-row stride (64 gates + 4 pad, 16B-aligned)
#define GPL  (BT * GRS + 8)   // 552: per-ks plane stride
#define GRF  (16 * GPL)       // 8832 floats per parity
#define U_FLOATS  (BT * KP)   // 4384
#define OP3F 32               // [4 waves][8 rows] out-proj partials per slot
#define LDS_FLOATS (U_FLOATS + 2 * GRF + 3 * OP3F)   // 22144 (88.6 KB)
#define LDS_BYTES  (LDS_FLOATS * 4)
#define PUB_U32  (2 * PODS * BT * HH)   // 65536 u32 (256 KB in d_ws)

typedef float f4v __attribute__((ext_vector_type(4)));
typedef float f2v __attribute__((ext_vector_type(2)));
typedef unsigned long long u64;
typedef unsigned int u32;

__device__ __forceinline__ float sigmf(float x)    { return 1.f / (1.f + __expf(-x)); }
__device__ __forceinline__ float tanhfast(float x) { return 1.f - 2.f / (__expf(2.f * x) + 1.f); }

// Thread (w, kap, gt) owns, for every chunk q=0..7, cols [128w+16q+4kap, +4)
// of the 4 gate rows {m*HH + j0 + gt} plus x-cols {8w+2kap, +1}. Packed f2v.
__device__ __forceinline__ void load_w(
    const float* __restrict__ Wih, const float* __restrict__ Whh,
    const float* __restrict__ bih, const float* __restrict__ bhh,
    int j0, int w, int kap, int gt,
    f2v w01[4][8], f2v w23[4][8], f2v wxv[4], float bias[4])
{
  #pragma unroll
  for (int m = 0; m < 4; ++m) {
    const int g = m * HH + j0 + gt;
    #pragma unroll
    for (int q = 0; q < 8; ++q) {
      const f4v tw = *(const f4v*)&Whh[g * HH + w * 128 + q * 16 + kap * 4];
      f2v a; a[0] = tw[0]; a[1] = tw[1]; w01[m][q] = a;
      f2v b; b[0] = tw[2]; b[1] = tw[3]; w23[m][q] = b;
    }
    wxv[m]  = *(const f2v*)&Wih[g * FF + w * 8 + kap * 2];
    bias[m] = bih[g] + bhh[g];
  }
}

__global__ void init_ws_kernel(u32* pub) {
  const int i = blockIdx.x * blockDim.x + threadIdx.x;
  if (i < PUB_U32) pub[i] = 0u;   // h = 0.0f, tag byte = 0 (both parities)
}

#define LDU64(P) __hip_atomic_load((P), __ATOMIC_RELAXED, __HIP_MEMORY_SCOPE_AGENT)

// Issue chunk Q's single u64 load (2 tagged u32 cols 16Q+2sub, +1) from base GP.
#define ISSUE(Q, GP) v[Q] = LDU64((const u64*)((GP) + 16 * (Q)))

// Wait chunk Q fresh (both halves' tag byte == tg), fast retry (sleep after 2
// rounds), strip tags, stage both cols with one 8B LDS write.
#define WAITCH(Q) do {                                                         \
    unsigned lo_ = (unsigned)v[Q], hi_ = (unsigned)(v[Q] >> 32);               \
    int tries = 0;                                                             \
    while ((lo_ & 255u) != tg || (hi_ & 255u) != tg) {                         \
      if (++tries > 2) __builtin_amdgcn_s_sleep(1);                            \
      v[Q] = LDU64((const u64*)(gp + 16 * (Q)));                               \
      lo_ = (unsigned)v[Q]; hi_ = (unsigned)(v[Q] >> 32);                      \
    }                                                                          \
    float2 st_;                                                                \
    st_.x = __uint_as_float(lo_ & ~255u);                                      \
    st_.y = __uint_as_float(hi_ & ~255u);                                      \
    *(float2*)&Us[16 * (Q)] = st_;                                             \
  } while (0)

// FMA on chunk Q: 8 rows x 4 cols x 4 gate types, packed float2 (pk_fma).
#define FMACHUNK(Q) do {                                                       \
    asm volatile("" ::: "memory");                                             \
    _Pragma("unroll")                                                          \
    for (int b = 0; b < 8; ++b) {                                              \
      const f4v u = *(const f4v*)&U[b * KP + w * 128 + 16 * (Q) + 4 * kap];    \
      f2v u01; u01[0] = u[0]; u01[1] = u[1];                                   \
      f2v u23; u23[0] = u[2]; u23[1] = u[3];                                   \
      _Pragma("unroll")                                                        \
      for (int m = 0; m < 4; ++m)                                              \
        acc2[m][b] += u01 * w01[m][Q] + u23 * w23[m][Q];                       \
    }                                                                          \
  } while (0)

__global__ void __launch_bounds__(NTHR, 1)
lstm_ae_kernel(const float* __restrict__ x,
               const float* __restrict__ eWih, const float* __restrict__ eWhh,
               const float* __restrict__ ebih, const float* __restrict__ ebhh,
               const float* __restrict__ dWih, const float* __restrict__ dWhh,
               const float* __restrict__ dbih, const float* __restrict__ dbhh,
               const float* __restrict__ Wo,  const float* __restrict__ bo,
               float* __restrict__ out, u32* __restrict__ pub)
{
  extern __shared__ float lds[];
  float* U   = lds;                      // [BT][KP]      h | x_t (wave-private cols)
  float* Gr  = lds + U_FLOATS;           // [2][16][GPL]  K-split partials (parity)
  float* OP3 = lds + U_FLOATS + 2 * GRF; // [3][4][8]     out-proj partials (mod-3)

  const int tid = threadIdx.x;
  const int blk = blockIdx.x;
  const int pod = blk & (PODS - 1);
  const int gb  = blk >> 3;          // 0..31 within pod
  const int b0  = pod * BT;
  const int j0  = gb * JT;

  const int w    = tid >> 6;         // wave 0..3: owns h cols [128w,128w+128)
  const int lane = tid & 63;
  const int row  = lane >> 3;        // batch row 0..7
  const int sub  = lane & 7;         // col-pair sub-offset within chunk

  const int ks  = tid >> 4;          // K-slice id 0..15 (Gr plane index)
  const int kap = ks & 3;            // chunk-column group 0..3
  const int gt  = tid & 15;          // hidden index within block

  // Update mapping (static across steps -> c stays in a register).
  const bool upd = tid < BT * JT;            // waves 0-1
  const int  ub  = tid >> 4, ujl = tid & 15;
  float c_reg = 0.f;

  f2v   w01[4][8], w23[4][8], wxv[4];
  float bias[4];
  load_w(eWih, eWhh, ebih, ebhh, j0, w, kap, gt, w01, w23, wxv, bias);

  // Gather state persists across iterations (all 8 chunks early-issued).
  u64 v[8];
  {
    const u32* gp0 = pub + (size_t)pod * (BT * HH) + row * HH + 128 * w + 2 * sub;
    ISSUE(0, gp0); ISSUE(1, gp0); ISSUE(2, gp0); ISSUE(3, gp0);
    ISSUE(4, gp0); ISSUE(5, gp0); ISSUE(6, gp0); ISSUE(7, gp0);
  }

  #pragma unroll 1
  for (int phase = 0; phase < 2; ++phase) {
    #pragma unroll 1
    for (int step = 0; step < TT; ++step) {
      const int s = phase * TT + step;       // global step 0..1023
      const unsigned tg = (unsigned)(s & 255);
      const int t = phase ? (TT - 1 - step) : step;
      const u32* prd = pub + (size_t)((s & 1) * PODS + pod) * (BT * HH);
      u32*       pwr = pub + (size_t)(((s + 1) & 1) * PODS + pod) * (BT * HH);
      float* Grp = Gr + (s & 1) * GRF;

      // ---- stage this wave's x slice ----
      U[row * KP + HH + w * 8 + sub] =
          x[((size_t)(b0 + row) * TT + t) * FF + w * 8 + sub];

      f2v acc2[4][8];
      #pragma unroll
      for (int m = 0; m < 4; ++m)
        #pragma unroll
        for (int b = 0; b < 8; ++b) {
          f2v z; z[0] = (ks == 0) ? bias[m] : 0.f; z[1] = 0.f;
          acc2[m][b] = z;
        }

      // ---- x-part FMA first (same-wave LDS, covers WAITCH(0)) ----
      #pragma unroll
      for (int b = 0; b < 8; ++b) {
        const f2v ux = *(const f2v*)&U[b * KP + HH + w * 8 + 2 * kap];
        #pragma unroll
        for (int m = 0; m < 4; ++m)
          acc2[m][b] += ux * wxv[m];
      }

      // ---- 8-chunk gather->FMA pipeline (ALL issued last step, post-publish) ----
      const u32* gp = prd + row * HH + 128 * w + 2 * sub;
      float*     Us = U + row * KP + 128 * w + 2 * sub;
      WAITCH(0); FMACHUNK(0);
      WAITCH(1); FMACHUNK(1);
      WAITCH(2); FMACHUNK(2);
      WAITCH(3); FMACHUNK(3);
      WAITCH(4); FMACHUNK(4);
      WAITCH(5); FMACHUNK(5);
      WAITCH(6); FMACHUNK(6);
      WAITCH(7); FMACHUNK(7);

      // ---- Gr write: 4 gates of (b, hidden gt) as one aligned f4v ----
      {
        float* Gw = Grp + ks * GPL + gt * 4;
        #pragma unroll
        for (int b = 0; b < 8; ++b) {
          f4v r;
          #pragma unroll
          for (int m = 0; m < 4; ++m) r[m] = acc2[m][b][0] + acc2[m][b][1];
          *(f4v*)&Gw[b * GRS] = r;
        }
      }
      __syncthreads();   // BAR A (the only barrier): Gr complete

      // ---- reduce 16 K-planes (f4v reads), activations, update, publish ----
      if (upd) {
        const float* g0 = Grp + ub * GRS + ujl * 4;
        float si = 0.f, sf = 0.f, sg = 0.f, so = 0.f;
        #pragma unroll
        for (int q = 0; q < 16; ++q) {
          const f4v g = *(const f4v*)(g0 + q * GPL);
          si += g[0]; sf += g[1]; sg += g[2]; so += g[3];
        }
        const float c2 = sigmf(sf) * c_reg + sigmf(si) * tanhfast(sg);
        const float h2 = sigmf(so) * tanhfast(c2);
        c_reg = c2;
        // mantissa-tag publish: low byte of the f32 carries (s+1)&255
        const unsigned pk = (__float_as_uint(h2) & ~255u)
                          | ((unsigned)(s + 1) & 255u);
        __hip_atomic_store(&pwr[ub * HH + j0 + ujl], pk,
                           __ATOMIC_RELAXED, __HIP_MEMORY_SCOPE_AGENT);
      }

      // ---- EARLY ISSUE all 8 chunks for step s+1, right after publish:
      // out-proj + OP3 + loop tail now cover the MALL round trip. ----
      {
        const u32* gpn = (const u32*)pwr + row * HH + 128 * w + 2 * sub;
        ISSUE(0, gpn); ISSUE(1, gpn); ISSUE(2, gpn); ISSUE(3, gpn);
        ISSUE(4, gpn); ISSUE(5, gpn); ISSUE(6, gpn); ISSUE(7, gpn);
        asm volatile("" ::: "memory");
      }

      // ---- decoder out-projection, POST-barrier (overlaps the gather RT).
      // Partial over this wave's own 128 U cols (pre-update h(t), faithful),
      // shfl-reduced over sub -> 8 floats/wave into OP3[s%3]; combined one
      // step later (BAR A of s+1 orders the writes; (s+1)%3 != (s-1)%3). ----
      if (phase) {
        const float* wrow = Wo + gb * HH + w * 128 + sub * 16;
        const float* urow = U + row * KP + w * 128 + sub * 16;
        float pj = 0.f;
        #pragma unroll
        for (int k = 0; k < 16; k += 4) {
          const f4v wvv = *(const f4v*)(wrow + k);
          const f4v uvv = *(const f4v*)(urow + k);
          pj += uvv[0] * wvv[0] + uvv[1] * wvv[1] + uvv[2] * wvv[2] + uvv[3] * wvv[3];
        }
        pj += __shfl_xor(pj, 1);
        pj += __shfl_xor(pj, 2);
        pj += __shfl_xor(pj, 4);
        if (sub == 0) OP3[(s % 3) * OP3F + w * 8 + row] = pj;
        // combine PREVIOUS decode step (t_prev = t+1)
        if (step > 0 && tid >= 192 && tid < 200) {
          const int b = tid - 192;
          const float* op = OP3 + ((s - 1) % 3) * OP3F + b;
          const float sm = op[0] + op[8] + op[16] + op[24];
          out[((size_t)(b0 + b) * TT + (t + 1)) * FF + gb] = sm + bo[gb];
        }
      }
    }
    if (phase == 0)  // encoder done: swap register weights to decoder
      load_w(dWih, dWhh, dbih, dbhh, j0, w, kap, gt, w01, w23, wxv, bias);
  }

  // ---- epilogue: combine the final decode step's out-proj (t = 0) ----
  __syncthreads();
  if (tid >= 192 && tid < 200) {
    const int b = tid - 192;
    const float* op = OP3 + ((2 * TT - 1) % 3) * OP3F + b;
    const float sm = op[0] + op[8] + op[16] + op[24];
    out[((size_t)(b0 + b) * TT + 0) * FF + gb] = sm + bo[gb];
  }
}

extern "C" void kernel_launch(void* const* d_in, const int* in_sizes, int n_in,
                              void* d_out, int out_size, void* d_ws, size_t ws_size,
                              hipStream_t stream) {
  const float* x    = (const float*)d_in[0];
  const float* eWih = (const float*)d_in[1];   // enc_Wih0 [2048,32]
  const float* eWhh = (const float*)d_in[2];   // enc_Whh0 [2048,512]
  const float* ebih = (const float*)d_in[3];
  const float* ebhh = (const float*)d_in[4];
  // d_in[5..8] enc layer 1: dead (only feeds dead decoder layer 1)
  const float* dWih = (const float*)d_in[9];   // dec_Wih0
  const float* dWhh = (const float*)d_in[10];  // dec_Whh0
  const float* dbih = (const float*)d_in[11];
  const float* dbhh = (const float*)d_in[12];
  // d_in[13..16] dec layer 1: dead (hB/cB never reach outs)
  const float* Wo   = (const float*)d_in[17];  // [32,512]
  const float* bo   = (const float*)d_in[18];  // [32]
  float* out = (float*)d_out;

  u32* pubbuf = (u32*)d_ws;                    // [2][8][8][512] tagged h (u32)

  hipFuncSetAttribute(reinterpret_cast<const void*>(lstm_ae_kernel),
                      hipFuncAttributeMaxDynamicSharedMemorySize, LDS_BYTES);

  init_ws_kernel<<<dim3((PUB_U32 + NTHR - 1) / NTHR), dim3(NTHR), 0, stream>>>(pubbuf);
  lstm_ae_kernel<<<dim3(NBLK), dim3(NTHR), LDS_BYTES, stream>>>(
      x, eWih, eWhh, ebih, ebhh, dWih, dWhh, dbih, dbhh, Wo, bo,
      out, pubbuf);
}

// Round 19
// 5541.002 us; speedup vs baseline: 2.1569x; 1.1881x over previous
//
#include <hip/hip_runtime.h>

// LSTMAutoEncoder: B=64, T=512, H=512, F=32.
// Dead-code: only encoder L0 (final h,c) and decoder L0 feed the output:
//   out[:, t, :] = h_dec0_before_step(511-t) @ W_out^T + b_out
// -> 1024 sequential cell steps; batch in 8 pods of 8 rows x 32 blocks.
//
// Round 19 = round 14 VERBATIM (best, 5.69ms) + ONE proven fix from r18:
// vectorized Gr (4 gates of (b,hidden) as one aligned f4v; GRS=68, GPL=552)
// -> reduce tail: 16x ds_read_b128 (was 64 scalar), write 8x ds_write_b128.
// r18's other change (all-8 early issue) REVERTED: issuing chunks 4-7 at
// publish time outruns slow producers -> stale first checks -> retry storm
// (FETCH 134->158MB, dur +0.9ms). r14's schedule (0-3 at step tail, 4-7
// mid-pipeline) is the correct issue spacing. Law (4x confirmed): tag-wait
// issue timing must track producer cadence; too early AND too late lose.

#define TT   512
#define HH   512
#define FF   32
#define KP   548              // U row stride (floats): 512 h + 32 x + pad
#define PODS 8
#define BT   8                // batch rows per pod
#define GBLK 32               // blocks per pod
#define JT   16               // hidden indices per block
#define NTHR 256
#define NBLK (PODS * GBLK)
#define GRS  68               // Gr batch-row stride (64 gates + 4 pad, 16B-aligned)
#define GPL  (BT * GRS + 8)   // 552: per-ks plane stride
#define GRF  (16 * GPL)       // 8832 floats per parity
#define U_FLOATS  (BT * KP)   // 4384
#define OP3F 32               // [4 waves][8 rows] out-proj partials per slot
#define LDS_FLOATS (U_FLOATS + 2 * GRF + 3 * OP3F)   // 22144 (88.6 KB)
#define LDS_BYTES  (LDS_FLOATS * 4)
#define PUB_U32  (2 * PODS * BT * HH)   // 65536 u32 (256 KB in d_ws)

typedef float f4v __attribute__((ext_vector_type(4)));
typedef float f2v __attribute__((ext_vector_type(2)));
typedef unsigned long long u64;
typedef unsigned int u32;

__device__ __forceinline__ float sigmf(float x)    { return 1.f / (1.f + __expf(-x)); }
__device__ __forceinline__ float tanhfast(float x) { return 1.f - 2.f / (__expf(2.f * x) + 1.f); }

// Thread (w, kap, gt) owns, for every chunk q=0..7, cols [128w+16q+4kap, +4)
// of the 4 gate rows {m*HH + j0 + gt} plus x-cols {8w+2kap, +1}. Packed f2v.
__device__ __forceinline__ void load_w(
    const float* __restrict__ Wih, const float* __restrict__ Whh,
    const float* __restrict__ bih, const float* __restrict__ bhh,
    int j0, int w, int kap, int gt,
    f2v w01[4][8], f2v w23[4][8], f2v wxv[4], float bias[4])
{
  #pragma unroll
  for (int m = 0; m < 4; ++m) {
    const int g = m * HH + j0 + gt;
    #pragma unroll
    for (int q = 0; q < 8; ++q) {
      const f4v tw = *(const f4v*)&Whh[g * HH + w * 128 + q * 16 + kap * 4];
      f2v a; a[0] = tw[0]; a[1] = tw[1]; w01[m][q] = a;
      f2v b; b[0] = tw[2]; b[1] = tw[3]; w23[m][q] = b;
    }
    wxv[m]  = *(const f2v*)&Wih[g * FF + w * 8 + kap * 2];
    bias[m] = bih[g] + bhh[g];
  }
}

__global__ void init_ws_kernel(u32* pub) {
  const int i = blockIdx.x * blockDim.x + threadIdx.x;
  if (i < PUB_U32) pub[i] = 0u;   // h = 0.0f, tag byte = 0 (both parities)
}

#define LDU64(P) __hip_atomic_load((P), __ATOMIC_RELAXED, __HIP_MEMORY_SCOPE_AGENT)

// Issue chunk Q's single u64 load (2 tagged u32 cols 16Q+2sub, +1) from base GP.
#define ISSUE(Q, GP) v[Q] = LDU64((const u64*)((GP) + 16 * (Q)))

// Wait chunk Q fresh (both halves' tag byte == tg), fast retry (sleep after 2
// rounds), strip tags, stage both cols with one 8B LDS write.
#define WAITCH(Q) do {                                                         \
    unsigned lo_ = (unsigned)v[Q], hi_ = (unsigned)(v[Q] >> 32);               \
    int tries = 0;                                                             \
    while ((lo_ & 255u) != tg || (hi_ & 255u) != tg) {                         \
      if (++tries > 2) __builtin_amdgcn_s_sleep(1);                            \
      v[Q] = LDU64((const u64*)(gp + 16 * (Q)));                               \
      lo_ = (unsigned)v[Q]; hi_ = (unsigned)(v[Q] >> 32);                      \
    }                                                                          \
    float2 st_;                                                                \
    st_.x = __uint_as_float(lo_ & ~255u);                                      \
    st_.y = __uint_as_float(hi_ & ~255u);                                      \
    *(float2*)&Us[16 * (Q)] = st_;                                             \
  } while (0)

// FMA on chunk Q: 8 rows x 4 cols x 4 gate types, packed float2 (pk_fma).
#define FMACHUNK(Q) do {                                                       \
    asm volatile("" ::: "memory");                                             \
    _Pragma("unroll")                                                          \
    for (int b = 0; b < 8; ++b) {                                              \
      const f4v u = *(const f4v*)&U[b * KP + w * 128 + 16 * (Q) + 4 * kap];    \
      f2v u01; u01[0] = u[0]; u01[1] = u[1];                                   \
      f2v u23; u23[0] = u[2]; u23[1] = u[3];                                   \
      _Pragma("unroll")                                                        \
      for (int m = 0; m < 4; ++m)                                              \
        acc2[m][b] += u01 * w01[m][Q] + u23 * w23[m][Q];                       \
    }                                                                          \
  } while (0)

__global__ void __launch_bounds__(NTHR, 1)
lstm_ae_kernel(const float* __restrict__ x,
               const float* __restrict__ eWih, const float* __restrict__ eWhh,
               const float* __restrict__ ebih, const float* __restrict__ ebhh,
               const float* __restrict__ dWih, const float* __restrict__ dWhh,
               const float* __restrict__ dbih, const float* __restrict__ dbhh,
               const float* __restrict__ Wo,  const float* __restrict__ bo,
               float* __restrict__ out, u32* __restrict__ pub)
{
  extern __shared__ float lds[];
  float* U   = lds;                      // [BT][KP]      h | x_t (wave-private cols)
  float* Gr  = lds + U_FLOATS;           // [2][16][GPL]  K-split partials (parity)
  float* OP3 = lds + U_FLOATS + 2 * GRF; // [3][4][8]     out-proj partials (mod-3)

  const int tid = threadIdx.x;
  const int blk = blockIdx.x;
  const int pod = blk & (PODS - 1);
  const int gb  = blk >> 3;          // 0..31 within pod
  const int b0  = pod * BT;
  const int j0  = gb * JT;

  const int w    = tid >> 6;         // wave 0..3: owns h cols [128w,128w+128)
  const int lane = tid & 63;
  const int row  = lane >> 3;        // batch row 0..7
  const int sub  = lane & 7;         // col-pair sub-offset within chunk

  const int ks  = tid >> 4;          // K-slice id 0..15 (Gr plane index)
  const int kap = ks & 3;            // chunk-column group 0..3
  const int gt  = tid & 15;          // hidden index within block

  // Update mapping (static across steps -> c stays in a register).
  const bool upd = tid < BT * JT;            // waves 0-1
  const int  ub  = tid >> 4, ujl = tid & 15;
  float c_reg = 0.f;

  f2v   w01[4][8], w23[4][8], wxv[4];
  float bias[4];
  load_w(eWih, eWhh, ebih, ebhh, j0, w, kap, gt, w01, w23, wxv, bias);

  // Gather state persists across iterations (early-issued chunks 0-3).
  u64 v[8];
  {
    const u32* gp0 = pub + (size_t)pod * (BT * HH) + row * HH + 128 * w + 2 * sub;
    ISSUE(0, gp0); ISSUE(1, gp0); ISSUE(2, gp0); ISSUE(3, gp0);
  }

  #pragma unroll 1
  for (int phase = 0; phase < 2; ++phase) {
    #pragma unroll 1
    for (int step = 0; step < TT; ++step) {
      const int s = phase * TT + step;       // global step 0..1023
      const unsigned tg = (unsigned)(s & 255);
      const int t = phase ? (TT - 1 - step) : step;
      const u32* prd = pub + (size_t)((s & 1) * PODS + pod) * (BT * HH);
      u32*       pwr = pub + (size_t)(((s + 1) & 1) * PODS + pod) * (BT * HH);
      float* Grp = Gr + (s & 1) * GRF;

      // ---- stage this wave's x slice (latency overlaps first wait) ----
      U[row * KP + HH + w * 8 + sub] =
          x[((size_t)(b0 + row) * TT + t) * FF + w * 8 + sub];

      f2v acc2[4][8];
      #pragma unroll
      for (int m = 0; m < 4; ++m)
        #pragma unroll
        for (int b = 0; b < 8; ++b) {
          f2v z; z[0] = (ks == 0) ? bias[m] : 0.f; z[1] = 0.f;
          acc2[m][b] = z;
        }

      // ---- 8-chunk gather->FMA pipeline (chunks 0-3 issued LAST step;
      // 4-7 issued mid-pipeline = correct producer-cadence spacing) ----
      const u32* gp = prd + row * HH + 128 * w + 2 * sub;
      float*     Us = U + row * KP + 128 * w + 2 * sub;

      WAITCH(0); ISSUE(4, gp); FMACHUNK(0);
      WAITCH(1); ISSUE(5, gp); FMACHUNK(1);
      WAITCH(2); ISSUE(6, gp); FMACHUNK(2);
      WAITCH(3); ISSUE(7, gp); FMACHUNK(3);
      WAITCH(4); FMACHUNK(4);
      WAITCH(5); FMACHUNK(5);
      WAITCH(6); FMACHUNK(6);
      WAITCH(7); FMACHUNK(7);

      // ---- x part (packed) ----
      #pragma unroll
      for (int b = 0; b < 8; ++b) {
        const f2v ux = *(const f2v*)&U[b * KP + HH + w * 8 + 2 * kap];
        #pragma unroll
        for (int m = 0; m < 4; ++m)
          acc2[m][b] += ux * wxv[m];
      }
      // ---- Gr write: 4 gates of (b, hidden gt) as one aligned f4v ----
      {
        float* Gw = Grp + ks * GPL + gt * 4;
        #pragma unroll
        for (int b = 0; b < 8; ++b) {
          f4v r;
          #pragma unroll
          for (int m = 0; m < 4; ++m) r[m] = acc2[m][b][0] + acc2[m][b][1];
          *(f4v*)&Gw[b * GRS] = r;
        }
      }
      __syncthreads();   // BAR A (the only barrier): Gr complete

      // ---- reduce 16 K-planes (f4v reads), activations, update, publish ----
      if (upd) {
        const float* g0 = Grp + ub * GRS + ujl * 4;
        float si = 0.f, sf = 0.f, sg = 0.f, so = 0.f;
        #pragma unroll
        for (int q = 0; q < 16; ++q) {
          const f4v g = *(const f4v*)(g0 + q * GPL);
          si += g[0]; sf += g[1]; sg += g[2]; so += g[3];
        }
        const float c2 = sigmf(sf) * c_reg + sigmf(si) * tanhfast(sg);
        const float h2 = sigmf(so) * tanhfast(c2);
        c_reg = c2;
        // mantissa-tag publish: low byte of the f32 carries (s+1)&255
        const unsigned pk = (__float_as_uint(h2) & ~255u)
                          | ((unsigned)(s + 1) & 255u);
        __hip_atomic_store(&pwr[ub * HH + j0 + ujl], pk,
                           __ATOMIC_RELAXED, __HIP_MEMORY_SCOPE_AGENT);
      }

      // ---- decoder out-projection, POST-barrier (overlaps reduce/publish).
      // Partial over this wave's own 128 U cols (pre-update h(t), faithful),
      // shfl-reduced over sub -> 8 floats/wave into OP3[s%3]; combined one
      // step later (BAR A of s+1 orders the writes; (s+1)%3 != (s-1)%3). ----
      if (phase) {
        const float* wrow = Wo + gb * HH + w * 128 + sub * 16;
        const float* urow = U + row * KP + w * 128 + sub * 16;
        float pj = 0.f;
        #pragma unroll
        for (int k = 0; k < 16; k += 4) {
          const f4v wvv = *(const f4v*)(wrow + k);
          const f4v uvv = *(const f4v*)(urow + k);
          pj += uvv[0] * wvv[0] + uvv[1] * wvv[1] + uvv[2] * wvv[2] + uvv[3] * wvv[3];
        }
        pj += __shfl_xor(pj, 1);
        pj += __shfl_xor(pj, 2);
        pj += __shfl_xor(pj, 4);
        if (sub == 0) OP3[(s % 3) * OP3F + w * 8 + row] = pj;
        // combine PREVIOUS decode step (t_prev = t+1)
        if (step > 0 && tid >= 192 && tid < 200) {
          const int b = tid - 192;
          const float* op = OP3 + ((s - 1) % 3) * OP3F + b;
          const float sm = op[0] + op[8] + op[16] + op[24];
          out[((size_t)(b0 + b) * TT + (t + 1)) * FF + gb] = sm + bo[gb];
        }
      }

      // ---- EARLY ISSUE: chunks 0-3 of step s+1 (next parity = pwr plane). ----
      {
        const u32* gpn = (const u32*)pwr + row * HH + 128 * w + 2 * sub;
        ISSUE(0, gpn); ISSUE(1, gpn); ISSUE(2, gpn); ISSUE(3, gpn);
        asm volatile("" ::: "memory");
      }
    }
    if (phase == 0)  // encoder done: swap register weights to decoder
      load_w(dWih, dWhh, dbih, dbhh, j0, w, kap, gt, w01, w23, wxv, bias);
  }

  // ---- epilogue: combine the final decode step's out-proj (t = 0) ----
  __syncthreads();
  if (tid >= 192 && tid < 200) {
    const int b = tid - 192;
    const float* op = OP3 + ((2 * TT - 1) % 3) * OP3F + b;
    const float sm = op[0] + op[8] + op[16] + op[24];
    out[((size_t)(b0 + b) * TT + 0) * FF + gb] = sm + bo[gb];
  }
}

extern "C" void kernel_launch(void* const* d_in, const int* in_sizes, int n_in,
                              void* d_out, int out_size, void* d_ws, size_t ws_size,
                              hipStream_t stream) {
  const float* x    = (const float*)d_in[0];
  const float* eWih = (const float*)d_in[1];   // enc_Wih0 [2048,32]
  const float* eWhh = (const float*)d_in[2];   // enc_Whh0 [2048,512]
  const float* ebih = (const float*)d_in[3];
  const float* ebhh = (const float*)d_in[4];
  // d_in[5..8] enc layer 1: dead (only feeds dead decoder layer 1)
  const float* dWih = (const float*)d_in[9];   // dec_Wih0
  const float* dWhh = (const float*)d_in[10];  // dec_Whh0
  const float* dbih = (const float*)d_in[11];
  const float* dbhh = (const float*)d_in[12];
  // d_in[13..16] dec layer 1: dead (hB/cB never reach outs)
  const float* Wo   = (const float*)d_in[17];  // [32,512]
  const float* bo   = (const float*)d_in[18];  // [32]
  float* out = (float*)d_out;

  u32* pubbuf = (u32*)d_ws;                    // [2][8][8][512] tagged h (u32)

  hipFuncSetAttribute(reinterpret_cast<const void*>(lstm_ae_kernel),
                      hipFuncAttributeMaxDynamicSharedMemorySize, LDS_BYTES);

  init_ws_kernel<<<dim3((PUB_U32 + NTHR - 1) / NTHR), dim3(NTHR), 0, stream>>>(pubbuf);
  lstm_ae_kernel<<<dim3(NBLK), dim3(NTHR), LDS_BYTES, stream>>>(
      x, eWih, eWhh, ebih, ebhh, dWih, dWhh, dbih, dbhh, Wo, bo,
      out, pubbuf);
}